// Round 1
// baseline (815.021 us; speedup 1.0000x reference)
//
#include <hip/hip_runtime.h>

#define N_NODES 100000
#define N_EDGES 20000
#define NNZ_CNT 1000000
#define D 64

// ---------------- Kernel A: XW1 = X @ W1^T + b1  (N x 64) ----------------
__global__ void k_xw1(const float* __restrict__ X, const float* __restrict__ W1,
                      const float* __restrict__ b1, float* __restrict__ XW1) {
    __shared__ float Ws[D][D + 1];   // +1 pad: (65c+k)%32 = (c+k)%32 -> 2-way, free
    __shared__ float Xs[4 * D];
    int t = threadIdx.x;
    for (int i = t; i < D * D; i += 256) Ws[i / D][i % D] = W1[i];
    int base = blockIdx.x * 4 * D;
    Xs[t] = X[base + t];
    __syncthreads();
    int r = t >> 6, c = t & 63;
    const float* xr = &Xs[r * D];
    float acc = b1[c];
#pragma unroll
    for (int k = 0; k < D; ++k) acc += xr[k] * Ws[c][k];
    XW1[base + t] = acc;
}

// ---------------- Kernel B: scatter XW1[vertex] -> Xe[edges], count deg ----------------
__global__ void k_scatter_edge(const int* __restrict__ vertex, const int* __restrict__ edges,
                               const float* __restrict__ XW1, float* __restrict__ Xe,
                               float* __restrict__ deg) {
    int lane = threadIdx.x & 63;
    int wid = (blockIdx.x * blockDim.x + threadIdx.x) >> 6;
    int nw = (gridDim.x * blockDim.x) >> 6;
    for (int i = wid; i < NNZ_CNT; i += nw) {
        int v = vertex[i];
        int e = edges[i];
        float val = XW1[v * D + lane];
        atomicAdd(&Xe[e * D + lane], val);
        if (lane == 0) atomicAdd(&deg[v], 1.0f);
    }
}

// ---------------- Kernel C: scatter Xe[edges] -> G[vertex] ----------------
__global__ void k_scatter_node(const int* __restrict__ vertex, const int* __restrict__ edges,
                               const float* __restrict__ Xe, float* __restrict__ G) {
    int lane = threadIdx.x & 63;
    int wid = (blockIdx.x * blockDim.x + threadIdx.x) >> 6;
    int nw = (gridDim.x * blockDim.x) >> 6;
    for (int i = wid; i < NNZ_CNT; i += nw) {
        int v = vertex[i];
        int e = edges[i];
        float val = Xe[e * D + lane];
        atomicAdd(&G[v * D + lane], val);
    }
}

// ---------------- Kernel D: node-level fused epilogue ----------------
// Xv[v] = deg[v]*X[v] @ W2a^T + G[v] @ W2b^T + deg[v]*b2
// out[v] = (0.5*Xv[v] + 0.5*X0[v]) @ W^T + bw
__global__ void k_final(const float* __restrict__ X, const float* __restrict__ X0,
                        const float* __restrict__ G, const float* __restrict__ deg,
                        const float* __restrict__ W2, const float* __restrict__ b2,
                        const float* __restrict__ W, const float* __restrict__ bw,
                        float* __restrict__ out) {
    __shared__ float W2a[D][D + 1];
    __shared__ float W2b[D][D + 1];
    __shared__ float Wm[D][D + 1];
    __shared__ float Xs[4 * D];
    __shared__ float Gs[4 * D];
    __shared__ float Ms[4 * D];
    __shared__ float degs[4];
    int t = threadIdx.x;
    for (int i = t; i < D * D; i += 256) {
        int c = i / D, k = i % D;
        W2a[c][k] = W2[c * 128 + k];
        W2b[c][k] = W2[c * 128 + 64 + k];
        Wm[c][k] = W[i];
    }
    int row0 = blockIdx.x * 4;
    int base = row0 * D;
    Xs[t] = X[base + t];
    Gs[t] = G[base + t];
    if (t < 4) degs[t] = deg[row0 + t];
    __syncthreads();
    int r = t >> 6, c = t & 63;
    float d = degs[r];
    const float* xr = &Xs[r * D];
    const float* gr = &Gs[r * D];
    float acc = d * b2[c];
#pragma unroll
    for (int k = 0; k < D; ++k) acc += (d * xr[k]) * W2a[c][k] + gr[k] * W2b[c][k];
    Ms[t] = 0.5f * acc + 0.5f * X0[base + t];
    __syncthreads();
    const float* mr = &Ms[r * D];
    float o = bw[c];
#pragma unroll
    for (int k = 0; k < D; ++k) o += mr[k] * Wm[c][k];
    out[base + t] = o;
}

extern "C" void kernel_launch(void* const* d_in, const int* in_sizes, int n_in,
                              void* d_out, int out_size, void* d_ws, size_t ws_size,
                              hipStream_t stream) {
    const float* X  = (const float*)d_in[0];
    const float* X0 = (const float*)d_in[1];
    const int* vertex = (const int*)d_in[2];
    const int* edges  = (const int*)d_in[3];
    const float* W1w = (const float*)d_in[4];
    const float* W1b = (const float*)d_in[5];
    const float* W2w = (const float*)d_in[6];
    const float* W2bias = (const float*)d_in[7];
    const float* Ww  = (const float*)d_in[8];
    const float* Wbias = (const float*)d_in[9];

    float* out = (float*)d_out;                 // N*64
    float* Xe  = out + (size_t)N_NODES * D;     // E*64 (second output)
    // workspace layout: buf (N*64, used as XW1 then reused as G), deg (N)
    float* buf = (float*)d_ws;
    float* deg = buf + (size_t)N_NODES * D;

    hipMemsetAsync(Xe, 0, (size_t)N_EDGES * D * sizeof(float), stream);
    hipMemsetAsync(deg, 0, (size_t)N_NODES * sizeof(float), stream);

    // A: XW1 = X @ W1^T + b1   (into buf)
    k_xw1<<<N_NODES / 4, 256, 0, stream>>>(X, W1w, W1b, buf);
    // B: Xe[e] += XW1[v]; deg[v] += 1
    k_scatter_edge<<<4096, 256, 0, stream>>>(vertex, edges, buf, Xe, deg);
    // reuse buf as G: zero it
    hipMemsetAsync(buf, 0, (size_t)N_NODES * D * sizeof(float), stream);
    // C: G[v] += Xe[e]
    k_scatter_node<<<4096, 256, 0, stream>>>(vertex, edges, Xe, buf);
    // D: fused node-level epilogue
    k_final<<<N_NODES / 4, 256, 0, stream>>>(X, X0, buf, deg, W2w, W2bias, Ww, Wbias, out);
}